// Round 3
// baseline (430.957 us; speedup 1.0000x reference)
//
#include <hip/hip_runtime.h>

#define NS    23      // columns per row (dose + 22 masks)
#define NSTR  22      // structures
#define ND    85      // dose bins in the loss
#define NB    256     // histogram bins
#define H     0.4f    // bin width (covers [0, 102.4))
#define INV_H 2.5f
#define EPSF  1.1920929e-07f
#define BLK   256
#define MAXB  768     // 3 blocks/CU x 256 CUs
#define TILE_F  (BLK * NS)    // 5888 floats per tile
#define TILE_F4 (TILE_F / 4)  // 1472 float4s

// ---------------- Pass 1: per-structure signed dose histogram ----------------
// +1 at bin(dose_true), -1 at bin(relu(dose_pred)) per structure membership.
// Register-prefetch double buffering: tile k+1 rides in VGPRs while tile k
// is processed from LDS, so global latency overlaps compute instead of being
// drained at the barrier.
__global__ __launch_bounds__(BLK, 3) void dvh_hist_kernel(
    const float* __restrict__ yt,     // y_true f32, N x 23
    const float* __restrict__ yp,     // y_pred f32, N x 23 (col 0 only)
    int N, int numTiles,
    int* __restrict__ g_hist,         // 22 x 256
    int* __restrict__ g_cnt_part)     // nBlocks x 22
{
    __shared__ int    shist[NSTR * NB];   // 22528 B
    __shared__ int    scnt[NSTR];
    __shared__ float4 stile4[TILE_F4];    // 23552 B
    float* st = (float*)stile4;

    const int tid = threadIdx.x;
    const long long totalF  = (long long)N * NS;
    const long long totalF4 = totalF >> 2;
    const float4* __restrict__ src4 = (const float4*)yt;

    for (int i = tid; i < NSTR * NB; i += BLK) shist[i] = 0;
    if (tid < NSTR) scnt[tid] = 0;

    int cs[NSTR];
#pragma unroll
    for (int s = 0; s < NSTR; ++s) cs[s] = 0;

    float4 r[6];
    float pp_next = 0.0f, pp_cur = 0.0f;

    auto prefetch = [&](int t) {
#pragma unroll
        for (int k = 0; k < 6; ++k) {
            int idx = tid + k * BLK;
            if (idx < TILE_F4) {
                long long g = (long long)t * TILE_F4 + idx;
                r[k] = (g < totalF4) ? src4[g] : make_float4(0.f, 0.f, 0.f, 0.f);
            }
        }
        long long row = (long long)t * BLK + tid;
        pp_next = (row < (long long)N) ? yp[row * NS] : 0.0f;
    };

    auto storeTile = [&](int t) {
#pragma unroll
        for (int k = 0; k < 6; ++k) {
            int idx = tid + k * BLK;
            if (idx < TILE_F4) stile4[idx] = r[k];
        }
        // generic tail guard (totalF % 4 != 0): scalar-load the last <=3 floats
        if ((totalF & 3) && t == numTiles - 1) {
            long long baseF = (long long)t * TILE_F;
            long long gi = (totalF4 << 2) + tid;
            if (gi < totalF) st[(int)(gi - baseF)] = yt[gi];
        }
    };

    auto process = [&](int t) {
        long long rem = (long long)N - (long long)t * BLK;
        int rows = rem < BLK ? (int)rem : BLK;
        if (tid < rows) {
            const float* row = st + tid * NS;
            float tv = row[0];
            int qt = (int)(tv * INV_H);
            qt = qt > 0 ? qt : 0;
            qt = qt < NB - 1 ? qt : NB - 1;
            float p = fmaxf(pp_cur, 0.0f);
            int qp = (int)(p * INV_H);
            qp = qp < NB - 1 ? qp : NB - 1;
            const unsigned int* rowu = (const unsigned int*)row;
#pragma unroll
            for (int s = 0; s < NSTR; ++s) {
                if (rowu[s + 1] != 0u) {     // mask values are 0.0f / 1.0f
                    atomicAdd(&shist[s * NB + qt], 1);
                    atomicAdd(&shist[s * NB + qp], -1);
                    cs[s]++;
                }
            }
        }
    };

    int t = blockIdx.x;                // grid <= numTiles guaranteed by launch
    prefetch(t);
    storeTile(t); pp_cur = pp_next;
    __syncthreads();                   // covers shist zero-init too

    for (int t2 = t + gridDim.x; ; t2 += gridDim.x) {
        bool more = t2 < numTiles;
        if (more) prefetch(t2);        // loads in flight while we process
        process(t);
        if (!more) break;
        __syncthreads();               // everyone done reading stile
        storeTile(t2); pp_cur = pp_next;
        __syncthreads();               // writes visible
        t = t2;
    }

    // ---- flush block-local results ----
#pragma unroll
    for (int s = 0; s < NSTR; ++s)
        if (cs[s]) atomicAdd(&scnt[s], cs[s]);
    __syncthreads();

    if (tid < NSTR) g_cnt_part[blockIdx.x * NSTR + tid] = scnt[tid];

    // staggered start to spread same-address atomic contention across blocks
    int off = (blockIdx.x * 131) % (NSTR * NB);
    for (int i = tid; i < NSTR * NB; i += BLK) {
        int j = i + off; if (j >= NSTR * NB) j -= NSTR * NB;
        int v = shist[j];
        if (v) atomicAdd(&g_hist[j], v);
    }
}

// ------- Pass 2: raw (dvh_t - dvh_p)[s,d]^2 via histogram x sigmoid ---------
// Division by totvol is deferred to pass 3 (constant per s, factors out).
__global__ void dvh_reduce_kernel(const int* __restrict__ g_hist,
                                  float* __restrict__ dsq)   // ND x NSTR
{
    int d = blockIdx.x;        // 0..84
    int lane = threadIdx.x;    // 0..63

    float acc[NSTR];
#pragma unroll
    for (int s = 0; s < NSTR; ++s) acc[s] = 0.0f;

#pragma unroll
    for (int j = 0; j < NB / 64; ++j) {
        int q = lane + 64 * j;
        float c = ((float)q + 0.5f) * H;
        float w = 1.0f / (1.0f + __expf((float)d - c));   // sigmoid(c - d)
#pragma unroll
        for (int s = 0; s < NSTR; ++s)
            acc[s] += w * (float)g_hist[s * NB + q];
    }

#pragma unroll
    for (int s = 0; s < NSTR; ++s) {
#pragma unroll
        for (int o = 32; o; o >>= 1) acc[s] += __shfl_xor(acc[s], o);
    }

    if (lane == 0) {
#pragma unroll
        for (int s = 0; s < NSTR; ++s) dsq[d * NSTR + s] = acc[s] * acc[s];
    }
}

// ------- Pass 3: totvol totals, per-structure L2 over d, sum, scale ---------
__global__ void dvh_final_kernel(const float* __restrict__ dsq,
                                 const int* __restrict__ g_cnt_part,
                                 int nBlocks,
                                 float* __restrict__ out)
{
    __shared__ int   scnt[NSTR];
    __shared__ float ssum[NSTR];
    int tid = threadIdx.x;
    if (tid < NSTR) { scnt[tid] = 0; ssum[tid] = 0.0f; }
    __syncthreads();

    int totC = nBlocks * NSTR;
    for (int i = tid; i < totC; i += BLK)
        atomicAdd(&scnt[i % NSTR], g_cnt_part[i]);
    for (int i = tid; i < ND * NSTR; i += BLK)
        atomicAdd(&ssum[i % NSTR], dsq[i]);
    __syncthreads();

    float r = 0.0f;
    if (tid < NSTR) r = sqrtf(ssum[tid]) / ((float)scnt[tid] + EPSF);
    if (tid < 64) {
#pragma unroll
        for (int o = 32; o; o >>= 1) r += __shfl_xor(r, o);
        if (tid == 0) out[0] = r / (float)(ND * NSTR);
    }
}

extern "C" void kernel_launch(void* const* d_in, const int* in_sizes, int n_in,
                              void* d_out, int out_size, void* d_ws, size_t ws_size,
                              hipStream_t stream) {
    const float* yt = (const float*)d_in[0];
    const float* yp = (const float*)d_in[1];
    int N = in_sizes[0] / NS;

    int*   g_hist     = (int*)d_ws;                              // 22528 B
    int*   g_cnt_part = (int*)((char*)d_ws + 22528);             // 768*22*4 = 67584 B
    float* dsq        = (float*)((char*)d_ws + 22528 + 67584);   // 7480 B

    hipMemsetAsync(g_hist, 0, NSTR * NB * sizeof(int), stream);

    int numTiles = (N + BLK - 1) / BLK;
    int nBlocks = numTiles < MAXB ? numTiles : MAXB;

    dvh_hist_kernel<<<nBlocks, BLK, 0, stream>>>(yt, yp, N, numTiles, g_hist, g_cnt_part);
    dvh_reduce_kernel<<<ND, 64, 0, stream>>>(g_hist, dsq);
    dvh_final_kernel<<<1, BLK, 0, stream>>>(dsq, g_cnt_part, nBlocks, (float*)d_out);
}

// Round 5
// 411.896 us; speedup vs baseline: 1.0463x; 1.0463x over previous
//
#include <hip/hip_runtime.h>

#define NS    23      // columns per row (dose + 22 masks)
#define NSTR  22      // structures
#define ND    85      // dose bins in the loss
#define NB    256     // histogram bins
#define H     0.4f    // bin width (covers [0, 102.4))
#define INV_H 2.5f
#define EPSF  1.1920929e-07f
#define BLK   256
#define MAXB  768     // 3 blocks/CU x 256 CUs
#define TILE_F  (BLK * NS)    // 5888 floats per tile
#define TILE_F4 (TILE_F / 4)  // 1472 float4s

// ---------------- Pass 1: per-structure signed dose histogram ----------------
// R2-proven structure (block tile + barriers). Single change vs R2: the
// per-row mask loop batches ALL LDS reads into a bitmask BEFORE issuing any
// LDS atomic, breaking the 22-link ds_read->atomic serial latency chain.
__global__ __launch_bounds__(BLK, 3) void dvh_hist_kernel(
    const float* __restrict__ yt,   // y_true  f32, N x 23
    const float* __restrict__ yp,   // y_pred  f32, N x 23 (only col 0 used)
    int N, int numTiles,
    int* __restrict__ g_hist,       // 22 x 256
    int* __restrict__ g_cnt)        // 22
{
    __shared__ int    shist[NSTR * NB];              // 22528 B
    __shared__ int    scnt[NSTR];
    __shared__ float4 stile4[TILE_F4];               // 23552 B
    float* st = (float*)stile4;

    const int tid = threadIdx.x;

    for (int i = tid; i < NSTR * NB; i += BLK) shist[i] = 0;
    if (tid < NSTR) scnt[tid] = 0;

    int cs[NSTR];
#pragma unroll
    for (int s = 0; s < NSTR; ++s) cs[s] = 0;

    const size_t totalF = (size_t)N * NS;

    for (int tile = blockIdx.x; tile < numTiles; tile += gridDim.x) {
        // ---- issue my yp col-0 gather FIRST (latency folds into barrier drain)
        size_t n = (size_t)tile * BLK + tid;
        float p = (n < (size_t)N) ? yp[n * NS] : 0.0f;

        // ---- stage y_true tile (flat, coalesced 16B) ----
        size_t baseF = (size_t)tile * (BLK * NS);
        int cntF = (int)((totalF - baseF) < (size_t)(BLK * NS)
                             ? (totalF - baseF) : (size_t)(BLK * NS));
        int nv = cntF >> 2;   // full float4 chunks
        const float4* src = (const float4*)(yt + baseF);  // 16B aligned
        for (int i = tid; i < nv; i += BLK) stile4[i] = src[i];
        for (int i = (nv << 2) + tid; i < cntF; i += BLK) st[i] = yt[baseF + i];
        __syncthreads();

        // ---- process rows: batch all LDS reads, then atomics ----
        int rows = cntF / NS;
        if (tid < rows) {
            const unsigned int* row = (const unsigned int*)(st + tid * NS);

            float t0 = __uint_as_float(row[0]);
            unsigned int bits = 0;
#pragma unroll
            for (int s = 0; s < NSTR; ++s)
                bits |= (row[s + 1] != 0u ? 1u : 0u) << s;   // 22 independent reads

            int qt = (int)(t0 * INV_H);
            qt = qt > 0 ? qt : 0;
            qt = qt < NB - 1 ? qt : NB - 1;
            float pr = fmaxf(p, 0.0f);
            int qp = (int)(pr * INV_H);
            qp = qp < NB - 1 ? qp : NB - 1;

#pragma unroll
            for (int s = 0; s < NSTR; ++s) cs[s] += (bits >> s) & 1u;

            unsigned int b = bits;            // ~3.3 set bits avg
            while (b) {
                int s = __builtin_ctz(b); b &= b - 1;
                atomicAdd(&shist[s * NB + qt], 1);
                atomicAdd(&shist[s * NB + qp], -1);
            }
        }
        __syncthreads();   // protect stile before next staging
    }

    // ---- flush block-local results (R2 verbatim) ----
#pragma unroll
    for (int s = 0; s < NSTR; ++s)
        if (cs[s]) atomicAdd(&scnt[s], cs[s]);
    __syncthreads();

    for (int i = tid; i < NSTR * NB; i += BLK) {
        int v = shist[i];
        if (v) atomicAdd(&g_hist[i], v);
    }
    if (tid < NSTR) {
        int v = scnt[tid];
        if (v) atomicAdd(&g_cnt[tid], v);
    }
}

// ---------------- Pass 2: diff[s,d]^2 via histogram x sigmoid (R2 verbatim) --
__global__ void dvh_reduce_kernel(const int* __restrict__ g_hist,
                                  const int* __restrict__ g_cnt,
                                  float* __restrict__ dsq)   // ND x NSTR
{
    int d = blockIdx.x;        // 0..84
    int lane = threadIdx.x;    // 0..63

    float acc[NSTR];
#pragma unroll
    for (int s = 0; s < NSTR; ++s) acc[s] = 0.0f;

#pragma unroll
    for (int j = 0; j < NB / 64; ++j) {
        int q = lane + 64 * j;
        float c = ((float)q + 0.5f) * H;
        float w = 1.0f / (1.0f + __expf((float)d - c));   // sigmoid(c - d)
#pragma unroll
        for (int s = 0; s < NSTR; ++s)
            acc[s] += w * (float)g_hist[s * NB + q];
    }

#pragma unroll
    for (int s = 0; s < NSTR; ++s) {
#pragma unroll
        for (int o = 32; o; o >>= 1) acc[s] += __shfl_xor(acc[s], o);
    }

    if (lane == 0) {
#pragma unroll
        for (int s = 0; s < NSTR; ++s) {
            float diff = acc[s] / ((float)g_cnt[s] + EPSF);
            dsq[d * NSTR + s] = diff * diff;
        }
    }
}

// ------- Pass 3: per-structure L2 over d, sum, scale (R2 verbatim) ----------
__global__ void dvh_final_kernel(const float* __restrict__ dsq,
                                 float* __restrict__ out)
{
    int s = threadIdx.x;   // 0..63
    float r = 0.0f;
    if (s < NSTR) {
        float a = 0.0f;
        for (int d = 0; d < ND; ++d) a += dsq[d * NSTR + s];
        r = sqrtf(a);
    }
#pragma unroll
    for (int o = 32; o; o >>= 1) r += __shfl_xor(r, o);
    if (s == 0) out[0] = r / (float)(ND * NSTR);
}

extern "C" void kernel_launch(void* const* d_in, const int* in_sizes, int n_in,
                              void* d_out, int out_size, void* d_ws, size_t ws_size,
                              hipStream_t stream) {
    const float* yt = (const float*)d_in[0];
    const float* yp = (const float*)d_in[1];
    int N = in_sizes[0] / NS;

    int*   g_hist = (int*)d_ws;                                    // 22528 B
    int*   g_cnt  = (int*)((char*)d_ws + NSTR * NB * 4);           // 88 B
    float* dsq    = (float*)((char*)d_ws + NSTR * NB * 4 + 128);   // 85*22*4 B

    hipMemsetAsync(d_ws, 0, NSTR * NB * 4 + 128, stream);

    int numTiles = (N + BLK - 1) / BLK;
    int grid = numTiles < MAXB ? numTiles : MAXB;

    dvh_hist_kernel<<<grid, BLK, 0, stream>>>(yt, yp, N, numTiles, g_hist, g_cnt);
    dvh_reduce_kernel<<<ND, 64, 0, stream>>>(g_hist, g_cnt, dsq);
    dvh_final_kernel<<<1, 64, 0, stream>>>(dsq, (float*)d_out);
}